// Round 5
// baseline (293.556 us; speedup 1.0000x reference)
//
#include <hip/hip_runtime.h>
#include <stdint.h>
#include <stddef.h>

// ---------------------------------------------------------------------------
// 4 GAE encoders, fp16 MFMA. All GEMMs: C = A @ B^T (A:[M][lda], B:[N][ldb]).
// fp32 inputs (X, adjacencies) are consumed DIRECTLY by the GEMMs via
// reg-staged load->cvt->swizzled ds_write (no fp16 materialization pass).
//   prep  : 12 weights -> fp16 transposed (LDS tiles)
//   step1 : P  = W1t @ X^T   (S=4, B=fp32 X reg-staged);  T1 = tanh(reduce P)
//   step2 : P  = Adj @ T1^T  (S=4, A=fp32 Adj reg-staged); Z1 = reduce P
//   step3 : T2 = tanh(W2t @ Z1^T)            (direct fp16)
//   step4 : P  = Adj @ T2^T  (S=8, A=fp32);  Z2 = reduce P
//   step5 : T3 = W3t @ Z2^T                  (direct fp16)
//   step6 : P  = Adj @ T3^T  (S=8, A=fp32);  Z3 = reduce P
//   step7 : OUT = sigmoid(Z3 @ Z3^T), K=64   (fp32 NT stores)
// fp32 split-K partials live in d_out (50.3 MB < 144 MB; dead before step7).
// ---------------------------------------------------------------------------

typedef __attribute__((ext_vector_type(8))) _Float16 half8;
typedef __attribute__((ext_vector_type(4))) float f32x4;

#define PAD 3072
#define MR  3000

static __device__ __forceinline__ void async_cp16(const _Float16* g, _Float16* l) {
    __builtin_amdgcn_global_load_lds((const __attribute__((address_space(1))) void*)g,
                                     (__attribute__((address_space(3))) void*)l, 16, 0, 0);
}

// ---------------- prep: weight transpose (LDS 64x64 tiles) --------
struct PrepArgs {
    const float* Wsrc[12];          // [enc*3 + layer]
    _Float16* Wdst[3];              // W1t, W2t, W3t bases
};

__global__ __launch_bounds__(256) void prep_w(PrepArgs p) {
    __shared__ _Float16 lt[64 * 64];
    const int b = blockIdx.x;
    const int t = threadIdx.x;
    // per-enc tiles: W1 48x4=192, W2 4x2=8, W3 2x2=4  (204/enc, 816 total)
    const int enc = b / 204;
    int rem = b - enc * 204;
    const float* src; _Float16* dst; int fi, fo, ldk, kt, rt;
    if (rem < 192) {
        src = p.Wsrc[enc * 3 + 0]; dst = p.Wdst[0] + (size_t)enc * 256 * PAD;
        fi = MR; fo = 256; ldk = PAD; kt = rem >> 2; rt = rem & 3;
    } else if (rem < 200) {
        rem -= 192;
        src = p.Wsrc[enc * 3 + 1]; dst = p.Wdst[1] + (size_t)enc * 128 * 256;
        fi = 256; fo = 128; ldk = 256; kt = rem >> 1; rt = rem & 1;
    } else {
        rem -= 200;
        src = p.Wsrc[enc * 3 + 2]; dst = p.Wdst[2] + (size_t)enc * 128 * 128;
        fi = 128; fo = 64; ldk = 128; kt = rem >> 1; rt = rem & 1;
    }
    const int k0 = kt * 64, r0 = rt * 64;
    {
        const int kr = t >> 2, cc = (t & 3) << 4;
        const int gk = k0 + kr;
        const bool kok = gk < fi;
        #pragma unroll
        for (int j = 0; j < 16; ++j) {
            const int gr = r0 + cc + j;
            const float v = (kok && gr < fo) ? src[(size_t)gk * fo + gr] : 0.f;
            lt[(cc + j) * 64 + kr] = (_Float16)v;
        }
    }
    __syncthreads();
    {
        const int rr = t >> 2, kk = (t & 3) << 4;
        half8 a  = *(half8*)&lt[rr * 64 + kk];
        half8 bb = *(half8*)&lt[rr * 64 + kk + 8];
        _Float16* dp = dst + (size_t)(r0 + rr) * ldk + k0 + kk;
        *(half8*)dp = a;
        *(half8*)(dp + 8) = bb;
    }
}

// ---------------- GEMM body: C = A @ B^T ----------------
struct GArgs {
    const _Float16* Aall; size_t aStride; int aMask;
    const _Float16* Ball; size_t bStride; int bMask;
    const float* F32[4];            // per-encoder fp32 operand (ASRC/BSRC=1)
    void* Call; size_t cStride;
    int M, Ncols, Kp, lda, ldb, ldc, mBound, nBound;
};

// OMODE: 0 = direct fp16 (opt tanh via ACT), 2 = fp32 sigmoid (LDS repack, NT),
//        3 = fp32 raw partial (LDS repack).  S = split-K factor.
// ASRC/BSRC: 1 = that operand is fp32 [MR][MR], reg-staged with cvt.
template<int ACT, int OMODE, int S, int ASRC, int BSRC>
static __device__ __forceinline__
void gemm_body(const GArgs& ga, int bx, int by, int bz, _Float16* smem)
{
    _Float16* As = smem;
    _Float16* Bs = smem + 8192;

    const int z   = bz;
    const int e   = z / S;
    const int ksl = z - e * S;
    const int Kslice = ga.Kp / S;
    const int kbase  = ksl * Kslice;

    const _Float16* A = ga.Aall + (size_t)(e & ga.aMask) * ga.aStride;
    const _Float16* B = ga.Ball + (size_t)(e & ga.bMask) * ga.bStride;
    const float*    F = ga.F32[e];

    const int tm = bx * 128;
    const int tn = by * 128;
    const int t    = threadIdx.x;
    const int lane = t & 63;
    const int w    = t >> 6;
    const int wm   = (w >> 1) * 64;
    const int wn   = (w & 1) * 64;
    const int lr   = lane & 15;
    const int lg   = lane >> 4;

    f32x4 acc[4][4];
    const f32x4 zero = {0.f, 0.f, 0.f, 0.f};
    #pragma unroll
    for (int i = 0; i < 4; ++i)
        #pragma unroll
        for (int j = 0; j < 4; ++j) acc[i][j] = zero;

    const int nkt = Kslice >> 6;
    for (int kt = 0; kt < nkt; ++kt) {
        const int k0 = kbase + (kt << 6);
        // async fp16 staging first (overlaps the reg-staged fp32 path below)
        if (!ASRC) {
            #pragma unroll
            for (int i = 0; i < 4; ++i) {
                const int c = t + i * 256;
                const int row = c >> 3, slot = c & 7;
                const int ss = slot ^ (row & 7);
                async_cp16(A + (size_t)(tm + row) * ga.lda + k0 + ss * 8, &As[c * 8]);
            }
        }
        if (!BSRC) {
            #pragma unroll
            for (int i = 0; i < 4; ++i) {
                const int c = t + i * 256;
                const int row = c >> 3, slot = c & 7;
                const int ss = slot ^ (row & 7);
                async_cp16(B + (size_t)(tn + row) * ga.ldb + k0 + ss * 8, &Bs[c * 8]);
            }
        }
        if (ASRC) {
            #pragma unroll
            for (int i = 0; i < 4; ++i) {
                const int c = t + i * 256;
                const int row = c >> 3, g = c & 7;
                const int grow = tm + row;
                const int gcol = k0 + g * 8;
                half8 h;
                if (grow < MR && gcol < MR) {
                    const float* ap = F + (size_t)grow * MR + gcol;
                    f32x4 v0 = *(const f32x4*)ap;
                    f32x4 v1 = *(const f32x4*)(ap + 4);
                    #pragma unroll
                    for (int j = 0; j < 4; ++j) { h[j] = (_Float16)v0[j]; h[4 + j] = (_Float16)v1[j]; }
                } else {
                    #pragma unroll
                    for (int j = 0; j < 8; ++j) h[j] = (_Float16)0.f;
                }
                *(half8*)&As[row * 64 + ((g ^ (row & 7)) << 3)] = h;
            }
        }
        if (BSRC) {
            #pragma unroll
            for (int i = 0; i < 4; ++i) {
                const int c = t + i * 256;
                const int row = c >> 3, g = c & 7;
                const int grow = tn + row;
                const int gcol = k0 + g * 8;
                half8 h;
                if (grow < MR && gcol < MR) {
                    const float* bp = F + (size_t)grow * MR + gcol;
                    f32x4 v0 = *(const f32x4*)bp;
                    f32x4 v1 = *(const f32x4*)(bp + 4);
                    #pragma unroll
                    for (int j = 0; j < 4; ++j) { h[j] = (_Float16)v0[j]; h[4 + j] = (_Float16)v1[j]; }
                } else {
                    #pragma unroll
                    for (int j = 0; j < 8; ++j) h[j] = (_Float16)0.f;
                }
                *(half8*)&Bs[row * 64 + ((g ^ (row & 7)) << 3)] = h;
            }
        }
        __syncthreads();

        #pragma unroll
        for (int ks = 0; ks < 2; ++ks) {
            half8 af[4], bf[4];
            #pragma unroll
            for (int mi = 0; mi < 4; ++mi) {
                const int ra = wm + mi * 16 + lr;
                const int s  = (ks * 4 + lg) ^ (ra & 7);
                af[mi] = *(const half8*)((const char*)As + ra * 128 + s * 16);
            }
            #pragma unroll
            for (int ni = 0; ni < 4; ++ni) {
                const int rb = wn + ni * 16 + lr;
                const int s  = (ks * 4 + lg) ^ (rb & 7);
                bf[ni] = *(const half8*)((const char*)Bs + rb * 128 + s * 16);
            }
            #pragma unroll
            for (int mi = 0; mi < 4; ++mi)
                #pragma unroll
                for (int ni = 0; ni < 4; ++ni)
                    acc[mi][ni] = __builtin_amdgcn_mfma_f32_16x16x32_f16(
                        af[mi], bf[ni], acc[mi][ni], 0, 0, 0);
        }
        __syncthreads();
    }

    // epilogue. D layout: col = lane&15, row = 4*(lane>>4)+reg (m89-verified).
    if (OMODE == 0) {
        _Float16* C = (_Float16*)ga.Call + (size_t)e * ga.cStride;
        #pragma unroll
        for (int mi = 0; mi < 4; ++mi)
            #pragma unroll
            for (int rr = 0; rr < 4; ++rr) {
                const int m = tm + wm + mi * 16 + lg * 4 + rr;
                #pragma unroll
                for (int ni = 0; ni < 4; ++ni) {
                    const int n = tn + wn + ni * 16 + lr;
                    float x = acc[mi][ni][rr];
                    if (ACT) x = tanhf(x);
                    const bool ok = (m < ga.M) && (n < ga.Ncols);
                    C[(size_t)m * ga.ldc + n] = ok ? (_Float16)x : (_Float16)0.f;
                }
            }
    } else {
        // fp32 LDS-repack epilogue: per-wave 32x64 staging, float4 stores.
        float* Cp = (float*)ga.Call + (size_t)(OMODE == 3 ? z : e) * ga.cStride;
        float* ep = (float*)smem + w * 2048;   // 32 rows x 64 cols
        #pragma unroll
        for (int hs = 0; hs < 2; ++hs) {
            __syncthreads();
            #pragma unroll
            for (int mi2 = 0; mi2 < 2; ++mi2)
                #pragma unroll
                for (int ni = 0; ni < 4; ++ni)
                    #pragma unroll
                    for (int rr = 0; rr < 4; ++rr) {
                        const int row = mi2 * 16 + lg * 4 + rr;
                        const int col = ni * 16 + lr;
                        const int sw  = (((row ^ (row >> 2)) & 3) << 4);
                        ep[row * 64 + (col ^ sw)] = acc[hs * 2 + mi2][ni][rr];
                    }
            __syncthreads();
            #pragma unroll
            for (int r2 = 0; r2 < 8; ++r2) {
                const int row = r2 * 4 + (lane >> 4);
                const int c4  = (lane & 15) * 4;
                const int sw  = (((row ^ (row >> 2)) & 3) << 4);
                f32x4 v = *(const f32x4*)&ep[row * 64 + (c4 ^ sw)];
                const int gm = tm + wm + hs * 32 + row;
                const int gn = tn + wn + c4;
                if (gm < ga.mBound && gn < ga.nBound) {
                    if (OMODE == 2) {
                        #pragma unroll
                        for (int j = 0; j < 4; ++j)
                            v[j] = 1.0f / (1.0f + __expf(-v[j]));
                        __builtin_nontemporal_store(v, (f32x4*)&Cp[(size_t)gm * ga.ldc + gn]);
                    } else {
                        *(f32x4*)&Cp[(size_t)gm * ga.ldc + gn] = v;
                    }
                }
            }
        }
    }
}

template<int ACT, int OMODE, int S, int ASRC, int BSRC>
__global__ __launch_bounds__(256, 2)
void gemm_bt(GArgs ga) {
    __shared__ _Float16 smem[16384];
    gemm_body<ACT, OMODE, S, ASRC, BSRC>(ga, blockIdx.x, blockIdx.y, blockIdx.z, smem);
}

// ---------------- split-K reduce: out = act(sum_s P[s]) in fp16 ----------
template<int ACT, int S>
__global__ __launch_bounds__(256)
void reduce_k(const float* __restrict__ P, _Float16* __restrict__ out, size_t region)
{
    const size_t e    = blockIdx.y;
    const size_t base = (size_t)(blockIdx.x * 256 + threadIdx.x) * 8;
    const float* p0 = P + e * S * region + base;
    f32x4 s0 = {0.f, 0.f, 0.f, 0.f}, s1 = s0;
    #pragma unroll
    for (int s = 0; s < S; ++s) {
        const float* p = p0 + (size_t)s * region;
        s0 += *(const f32x4*)p;
        s1 += *(const f32x4*)(p + 4);
    }
    half8 h;
    #pragma unroll
    for (int j = 0; j < 8; ++j) {
        float x = (j < 4) ? s0[j] : s1[j - 4];
        if (ACT) x = tanhf(x);
        h[j] = (_Float16)x;
    }
    *(half8*)(out + e * region + base) = h;
}

// ---------------- launcher ----------------
extern "C" void kernel_launch(void* const* d_in, const int* in_sizes, int n_in,
                              void* d_out, int out_size, void* d_ws, size_t ws_size,
                              hipStream_t stream)
{
    const float* X1 = (const float*)d_in[0];
    const float* X2 = (const float*)d_in[1];

    const size_t R1 = 786432;   // 256*3072 and 3072*256
    const size_t R2 = 393216;   // 128*3072 and 3072*128

    // d_out: fp32 split-K partials (max 50.3 MB), dead before step7.
    float* Part = (float*)d_out;

    _Float16* hb = (_Float16*)d_ws;
    size_t off = 0;
    auto alloc = [&](size_t elems) { _Float16* p = hb + off; off += elems; return p; };
    _Float16* T1  = alloc(4 * R1);
    _Float16* Z1  = alloc(4 * R1);
    _Float16* T2  = alloc(4 * R2);
    _Float16* Z2  = alloc(4 * R2);
    _Float16* T3  = alloc(4 * R2);
    _Float16* Z3  = alloc(4 * R2);
    _Float16* W1t = alloc(4ull * 256 * PAD);
    _Float16* W2t = alloc(4ull * 128 * 256);
    _Float16* W3t = alloc(4ull * 128 * 128);

    // prep: weights -> fp16 transposed
    PrepArgs pa;
    for (int enc = 0; enc < 4; ++enc)
        for (int li = 0; li < 3; ++li)
            pa.Wsrc[enc * 3 + li] = (const float*)d_in[6 + enc * 3 + li];
    pa.Wdst[0] = W1t; pa.Wdst[1] = W2t; pa.Wdst[2] = W3t;
    prep_w<<<dim3(816, 1, 1), 256, 0, stream>>>(pa);

    const int BIG = 1 << 30;

    // step1: P = W1t @ X^T  M=256 N=3072 K=3072, S=4, B = fp32 X reg-staged
    GArgs g1 = { W1t, (size_t)256 * PAD, 3, nullptr, 0, 0,
                 { X1, X2, X1, X2 },
                 Part, R1, 256, PAD, PAD, PAD, MR, PAD, BIG, BIG };
    gemm_bt<0, 3, 4, 0, 1><<<dim3(2, 24, 16), 256, 0, stream>>>(g1);
    reduce_k<1, 4><<<dim3(384, 4, 1), 256, 0, stream>>>(Part, T1, R1);

    // step2: P = Adj @ T1^T  M=3072 N=256 K=3072, S=4, A = fp32 Adj reg-staged
    GArgs g2 = { nullptr, 0, 0, T1, R1, 3,
                 { (const float*)d_in[2], (const float*)d_in[3],
                   (const float*)d_in[4], (const float*)d_in[5] },
                 Part, R1, PAD, 256, PAD, MR, PAD, 256, BIG, BIG };
    gemm_bt<0, 3, 4, 1, 0><<<dim3(24, 2, 16), 256, 0, stream>>>(g2);
    reduce_k<0, 4><<<dim3(384, 4, 1), 256, 0, stream>>>(Part, Z1, R1);

    // step3: T2 = tanh(W2t @ Z1^T)  M=128 N=3072 K=256, direct
    GArgs g3 = { W2t, (size_t)128 * 256, 3, Z1, R1, 3,
                 { nullptr, nullptr, nullptr, nullptr },
                 T2, R2, 128, PAD, 256, 256, 256, PAD, BIG, BIG };
    gemm_bt<1, 0, 1, 0, 0><<<dim3(1, 24, 4), 256, 0, stream>>>(g3);

    // step4: P = Adj @ T2^T  M=3072 N=128 K=3072, S=8, A = fp32 Adj
    GArgs g4 = { nullptr, 0, 0, T2, R2, 3,
                 { (const float*)d_in[2], (const float*)d_in[3],
                   (const float*)d_in[4], (const float*)d_in[5] },
                 Part, R2, PAD, 128, PAD, MR, PAD, 128, BIG, BIG };
    gemm_bt<0, 3, 8, 1, 0><<<dim3(24, 1, 32), 256, 0, stream>>>(g4);
    reduce_k<0, 8><<<dim3(192, 4, 1), 256, 0, stream>>>(Part, Z2, R2);

    // step5: T3 = W3t @ Z2^T  M=128 N=3072 K=128, direct
    GArgs g5 = { W3t, (size_t)128 * 128, 3, Z2, R2, 3,
                 { nullptr, nullptr, nullptr, nullptr },
                 T3, R2, 128, PAD, 128, 128, 128, PAD, BIG, BIG };
    gemm_bt<0, 0, 1, 0, 0><<<dim3(1, 24, 4), 256, 0, stream>>>(g5);

    // step6: P = Adj @ T3^T  M=3072 N=128 K=3072, S=8, A = fp32 Adj
    GArgs g6 = { nullptr, 0, 0, T3, R2, 3,
                 { (const float*)d_in[2], (const float*)d_in[3],
                   (const float*)d_in[4], (const float*)d_in[5] },
                 Part, R2, PAD, 128, PAD, MR, PAD, 128, BIG, BIG };
    gemm_bt<0, 3, 8, 1, 0><<<dim3(24, 1, 32), 256, 0, stream>>>(g6);
    reduce_k<0, 8><<<dim3(192, 4, 1), 256, 0, stream>>>(Part, Z3, R2);

    // step7: OUT = sigmoid(Z3 @ Z3^T)  M=N=3000 K=64 (cols 64..127 of Z3 zero)
    GArgs g7 = { Z3, R2, 3, Z3, R2, 3,
                 { nullptr, nullptr, nullptr, nullptr },
                 d_out, (size_t)MR * MR, MR, MR, 64, 128, 128, MR, MR, MR };
    gemm_bt<0, 2, 1, 0, 0><<<dim3(24, 24, 4), 256, 0, stream>>>(g7);
}

// Round 6
// 275.015 us; speedup vs baseline: 1.0674x; 1.0674x over previous
//
#include <hip/hip_runtime.h>
#include <stdint.h>
#include <stddef.h>

// ---------------------------------------------------------------------------
// 4 GAE encoders, fp16 MFMA. All GEMMs: C = A @ B^T (A:[M][lda], B:[N][ldb]),
// both operands fp16 staged via global_load_lds (pre-swizzled source).
//   prep_all : X1,X2 + 4 adjacencies -> fp16 padded [3072][3072] (cached loads)
//              + 12 weights -> fp16 transposed (LDS 64x64 tiles)
//   step1 : P = W1t @ Xh^T  (S=4);  T1 = tanh(reduce P)
//   step2 : P = Adj @ T1^T  (S=4);  Z1 = reduce P
//   step3 : T2 = tanh(W2t @ Z1^T)   (direct)
//   step4 : P = Adj @ T2^T  (S=8);  Z2 = reduce P
//   step5 : T3 = W3t @ Z2^T         (direct)
//   step6 : P = Adj @ T3^T  (S=8);  Z3 = reduce P
//   step7 : OUT = sigmoid(Z3 @ Z3^T), K=64  (fp32 NT stores)
// d_out layout: [4 x fp16 Adj 75.5 MB][fp32 split-K partials <=50.3 MB]
// (both dead before step7 overwrites d_out).  Xh + intermediates in d_ws
// (~70 MB, same budget as round 1).
// ---------------------------------------------------------------------------

typedef __attribute__((ext_vector_type(8))) _Float16 half8;
typedef __attribute__((ext_vector_type(4))) float f32x4;

#define PAD 3072
#define MR  3000
#define SQ_STRIDE ((size_t)PAD * PAD)

static __device__ __forceinline__ void async_cp16(const _Float16* g, _Float16* l) {
    __builtin_amdgcn_global_load_lds((const __attribute__((address_space(1))) void*)g,
                                     (__attribute__((address_space(3))) void*)l, 16, 0, 0);
}

// ---------------- prep: 6 square casts + 12 weight transposes ----------
struct PrepArgs {
    const float* csrc[6];  _Float16* cdst[6];   // X1,X2,adj0..3
    const float* Wsrc[12]; _Float16* Wdst[3];   // W1t, W2t, W3t bases
};

__global__ __launch_bounds__(256) void prep_all(PrepArgs p) {
    __shared__ _Float16 lt[64 * 64];
    const int b = blockIdx.x;
    const int t = threadIdx.x;
    if (b < 13824) {
        // fp32 [3000][3000] -> fp16 [3072][3072] zero-padded. Cached loads
        // (inputs are L3-resident across iterations; NT loads would force HBM).
        const int arr = b / 2304;
        const int idx = (b - arr * 2304) * 256 + t;
        const int row = idx / 192;
        const int c0  = (idx - row * 192) * 16;
        const float* sp = p.csrc[arr] + (size_t)row * MR + c0;
        _Float16* d = p.cdst[arr] + (size_t)row * PAD + c0;
        half8 h0, h1;
        if (row < MR && c0 + 16 <= MR) {
            f32x4 v0 = *(const f32x4*)sp;
            f32x4 v1 = *(const f32x4*)(sp + 4);
            f32x4 v2 = *(const f32x4*)(sp + 8);
            f32x4 v3 = *(const f32x4*)(sp + 12);
            #pragma unroll
            for (int j = 0; j < 4; ++j) {
                h0[j] = (_Float16)v0[j]; h0[4 + j] = (_Float16)v1[j];
                h1[j] = (_Float16)v2[j]; h1[4 + j] = (_Float16)v3[j];
            }
        } else if (row < MR && c0 < MR) {
            #pragma unroll
            for (int j = 0; j < 8; ++j) {
                h0[j] = (c0 + j     < MR) ? (_Float16)sp[j]     : (_Float16)0.f;
                h1[j] = (c0 + 8 + j < MR) ? (_Float16)sp[8 + j] : (_Float16)0.f;
            }
        } else {
            #pragma unroll
            for (int j = 0; j < 8; ++j) { h0[j] = (_Float16)0.f; h1[j] = (_Float16)0.f; }
        }
        *(half8*)d = h0;
        *(half8*)(d + 8) = h1;
    } else {
        // weight transpose-cast: src [fi][fo] fp32 -> dst [fo_pad][ldk] fp16
        // per-enc tiles: W1 48x4=192, W2 4x2=8, W3 2x2=4  (204/enc, 816 total)
        const int b2  = b - 13824;
        const int enc = b2 / 204;
        int rem = b2 - enc * 204;
        const float* src; _Float16* dst; int fi, fo, ldk, kt, rt;
        if (rem < 192) {
            src = p.Wsrc[enc * 3 + 0]; dst = p.Wdst[0] + (size_t)enc * 256 * PAD;
            fi = MR; fo = 256; ldk = PAD; kt = rem >> 2; rt = rem & 3;
        } else if (rem < 200) {
            rem -= 192;
            src = p.Wsrc[enc * 3 + 1]; dst = p.Wdst[1] + (size_t)enc * 128 * 256;
            fi = 256; fo = 128; ldk = 256; kt = rem >> 1; rt = rem & 1;
        } else {
            rem -= 200;
            src = p.Wsrc[enc * 3 + 2]; dst = p.Wdst[2] + (size_t)enc * 128 * 128;
            fi = 128; fo = 64; ldk = 128; kt = rem >> 1; rt = rem & 1;
        }
        const int k0 = kt * 64, r0 = rt * 64;
        {
            const int kr = t >> 2, cc = (t & 3) << 4;
            const int gk = k0 + kr;
            const bool kok = gk < fi;
            #pragma unroll
            for (int j = 0; j < 16; ++j) {
                const int gr = r0 + cc + j;
                const float v = (kok && gr < fo) ? src[(size_t)gk * fo + gr] : 0.f;
                lt[(cc + j) * 64 + kr] = (_Float16)v;
            }
        }
        __syncthreads();
        {
            const int rr = t >> 2, kk = (t & 3) << 4;
            half8 a  = *(half8*)&lt[rr * 64 + kk];
            half8 bb = *(half8*)&lt[rr * 64 + kk + 8];
            _Float16* dp = dst + (size_t)(r0 + rr) * ldk + k0 + kk;
            *(half8*)dp = a;
            *(half8*)(dp + 8) = bb;
        }
    }
}

// ---------------- GEMM: C = A @ B^T ----------------
struct GArgs {
    const _Float16* Aall; size_t aStride; int aMask;
    const _Float16* Ball; size_t bStride; int bMask;
    void* Call; size_t cStride;
    int M, Ncols, Kp, lda, ldb, ldc, mBound, nBound;
};

// OMODE: 0 = direct fp16 (opt tanh via ACT), 2 = fp32 sigmoid (LDS repack, NT),
//        3 = fp32 raw partial (LDS repack).  S = split-K factor.
template<int ACT, int OMODE, int S>
__global__ __launch_bounds__(256, 3)
void gemm_bt(GArgs ga)
{
    __shared__ _Float16 smem[16384];
    _Float16* As = smem;
    _Float16* Bs = smem + 8192;

    const int z   = blockIdx.z;
    const int e   = z / S;
    const int ksl = z - e * S;
    const int Kslice = ga.Kp / S;
    const int kbase  = ksl * Kslice;

    const _Float16* A = ga.Aall + (size_t)(e & ga.aMask) * ga.aStride;
    const _Float16* B = ga.Ball + (size_t)(e & ga.bMask) * ga.bStride;

    const int tm = blockIdx.x * 128;
    const int tn = blockIdx.y * 128;
    const int t    = threadIdx.x;
    const int lane = t & 63;
    const int w    = t >> 6;
    const int wm   = (w >> 1) * 64;
    const int wn   = (w & 1) * 64;
    const int lr   = lane & 15;
    const int lg   = lane >> 4;

    f32x4 acc[4][4];
    const f32x4 zero = {0.f, 0.f, 0.f, 0.f};
    #pragma unroll
    for (int i = 0; i < 4; ++i)
        #pragma unroll
        for (int j = 0; j < 4; ++j) acc[i][j] = zero;

    const int nkt = Kslice >> 6;
    for (int kt = 0; kt < nkt; ++kt) {
        const int k0 = kbase + (kt << 6);
        // stage A,B tiles (128x64 fp16); LDS linear, source pre-swizzled so
        // reads can XOR-swizzle (slot ^= row&7) -> conflict-free ds_read_b128.
        #pragma unroll
        for (int i = 0; i < 4; ++i) {
            const int c = t + i * 256;
            const int row = c >> 3, slot = c & 7;
            const int ss = slot ^ (row & 7);
            async_cp16(A + (size_t)(tm + row) * ga.lda + k0 + ss * 8, &As[c * 8]);
        }
        #pragma unroll
        for (int i = 0; i < 4; ++i) {
            const int c = t + i * 256;
            const int row = c >> 3, slot = c & 7;
            const int ss = slot ^ (row & 7);
            async_cp16(B + (size_t)(tn + row) * ga.ldb + k0 + ss * 8, &Bs[c * 8]);
        }
        __syncthreads();

        #pragma unroll
        for (int ks = 0; ks < 2; ++ks) {
            half8 af[4], bf[4];
            #pragma unroll
            for (int mi = 0; mi < 4; ++mi) {
                const int ra = wm + mi * 16 + lr;
                const int s  = (ks * 4 + lg) ^ (ra & 7);
                af[mi] = *(const half8*)((const char*)As + ra * 128 + s * 16);
            }
            #pragma unroll
            for (int ni = 0; ni < 4; ++ni) {
                const int rb = wn + ni * 16 + lr;
                const int s  = (ks * 4 + lg) ^ (rb & 7);
                bf[ni] = *(const half8*)((const char*)Bs + rb * 128 + s * 16);
            }
            #pragma unroll
            for (int mi = 0; mi < 4; ++mi)
                #pragma unroll
                for (int ni = 0; ni < 4; ++ni)
                    acc[mi][ni] = __builtin_amdgcn_mfma_f32_16x16x32_f16(
                        af[mi], bf[ni], acc[mi][ni], 0, 0, 0);
        }
        __syncthreads();
    }

    // epilogue. D layout: col = lane&15, row = 4*(lane>>4)+reg (m89-verified).
    if (OMODE == 0) {
        _Float16* C = (_Float16*)ga.Call + (size_t)e * ga.cStride;
        #pragma unroll
        for (int mi = 0; mi < 4; ++mi)
            #pragma unroll
            for (int rr = 0; rr < 4; ++rr) {
                const int m = tm + wm + mi * 16 + lg * 4 + rr;
                #pragma unroll
                for (int ni = 0; ni < 4; ++ni) {
                    const int n = tn + wn + ni * 16 + lr;
                    float x = acc[mi][ni][rr];
                    if (ACT) x = tanhf(x);
                    const bool ok = (m < ga.M) && (n < ga.Ncols);
                    C[(size_t)m * ga.ldc + n] = ok ? (_Float16)x : (_Float16)0.f;
                }
            }
    } else {
        // fp32 LDS-repack epilogue: per-wave 32x64 staging, float4 stores.
        float* Cp = (float*)ga.Call + (size_t)(OMODE == 3 ? z : e) * ga.cStride;
        float* ep = (float*)smem + w * 2048;   // 32 rows x 64 cols
        #pragma unroll
        for (int hs = 0; hs < 2; ++hs) {
            __syncthreads();
            #pragma unroll
            for (int mi2 = 0; mi2 < 2; ++mi2)
                #pragma unroll
                for (int ni = 0; ni < 4; ++ni)
                    #pragma unroll
                    for (int rr = 0; rr < 4; ++rr) {
                        const int row = mi2 * 16 + lg * 4 + rr;
                        const int col = ni * 16 + lr;
                        const int sw  = (((row ^ (row >> 2)) & 3) << 4);
                        ep[row * 64 + (col ^ sw)] = acc[hs * 2 + mi2][ni][rr];
                    }
            __syncthreads();
            #pragma unroll
            for (int r2 = 0; r2 < 8; ++r2) {
                const int row = r2 * 4 + (lane >> 4);
                const int c4  = (lane & 15) * 4;
                const int sw  = (((row ^ (row >> 2)) & 3) << 4);
                f32x4 v = *(const f32x4*)&ep[row * 64 + (c4 ^ sw)];
                const int gm = tm + wm + hs * 32 + row;
                const int gn = tn + wn + c4;
                if (gm < ga.mBound && gn < ga.nBound) {
                    if (OMODE == 2) {
                        #pragma unroll
                        for (int j = 0; j < 4; ++j)
                            v[j] = 1.0f / (1.0f + __expf(-v[j]));
                        __builtin_nontemporal_store(v, (f32x4*)&Cp[(size_t)gm * ga.ldc + gn]);
                    } else {
                        *(f32x4*)&Cp[(size_t)gm * ga.ldc + gn] = v;
                    }
                }
            }
        }
    }
}

// ---------------- split-K reduce: out = act(sum_s P[s]) in fp16 ----------
template<int ACT, int S>
__global__ __launch_bounds__(256)
void reduce_k(const float* __restrict__ P, _Float16* __restrict__ out, size_t region)
{
    const size_t e    = blockIdx.y;
    const size_t base = (size_t)(blockIdx.x * 256 + threadIdx.x) * 8;
    const float* p0 = P + e * S * region + base;
    f32x4 s0 = {0.f, 0.f, 0.f, 0.f}, s1 = s0;
    #pragma unroll
    for (int s = 0; s < S; ++s) {
        const float* p = p0 + (size_t)s * region;
        s0 += *(const f32x4*)p;
        s1 += *(const f32x4*)(p + 4);
    }
    half8 h;
    #pragma unroll
    for (int j = 0; j < 8; ++j) {
        float x = (j < 4) ? s0[j] : s1[j - 4];
        if (ACT) x = tanhf(x);
        h[j] = (_Float16)x;
    }
    *(half8*)(out + e * region + base) = h;
}

// ---------------- launcher ----------------
extern "C" void kernel_launch(void* const* d_in, const int* in_sizes, int n_in,
                              void* d_out, int out_size, void* d_ws, size_t ws_size,
                              hipStream_t stream)
{
    const size_t R1 = 786432;   // 256*3072 and 3072*256
    const size_t R2 = 393216;   // 128*3072 and 3072*128

    // d_out layout: [4 x fp16 Adj (75.5 MB)][fp32 Part (<=50.3 MB)]
    _Float16* Adj  = (_Float16*)d_out;
    float*    Part = (float*)(Adj + 4 * SQ_STRIDE);

    _Float16* hb = (_Float16*)d_ws;
    size_t off = 0;
    auto alloc = [&](size_t elems) { _Float16* p = hb + off; off += elems; return p; };
    _Float16* Xh  = alloc(2 * SQ_STRIDE);
    _Float16* T1  = alloc(4 * R1);
    _Float16* Z1  = alloc(4 * R1);
    _Float16* T2  = alloc(4 * R2);
    _Float16* Z2  = alloc(4 * R2);
    _Float16* T3  = alloc(4 * R2);
    _Float16* Z3  = alloc(4 * R2);
    _Float16* W1t = alloc(4ull * 256 * PAD);
    _Float16* W2t = alloc(4ull * 128 * 256);
    _Float16* W3t = alloc(4ull * 128 * 128);

    // prep: all casts in one streaming kernel
    PrepArgs pa;
    pa.csrc[0] = (const float*)d_in[0]; pa.cdst[0] = Xh;
    pa.csrc[1] = (const float*)d_in[1]; pa.cdst[1] = Xh + SQ_STRIDE;
    for (int i = 0; i < 4; ++i) {
        pa.csrc[2 + i] = (const float*)d_in[2 + i];
        pa.cdst[2 + i] = Adj + (size_t)i * SQ_STRIDE;
    }
    for (int enc = 0; enc < 4; ++enc)
        for (int li = 0; li < 3; ++li)
            pa.Wsrc[enc * 3 + li] = (const float*)d_in[6 + enc * 3 + li];
    pa.Wdst[0] = W1t; pa.Wdst[1] = W2t; pa.Wdst[2] = W3t;
    prep_all<<<dim3(14640, 1, 1), 256, 0, stream>>>(pa);

    const int BIG = 1 << 30;

    // step1: P = W1t @ Xh^T  M=256 N=3072 K=3072, S=4
    GArgs g1 = { W1t, (size_t)256 * PAD, 3, Xh, SQ_STRIDE, 1,
                 Part, R1, 256, PAD, PAD, PAD, PAD, PAD, BIG, BIG };
    gemm_bt<0, 3, 4><<<dim3(2, 24, 16), 256, 0, stream>>>(g1);
    reduce_k<1, 4><<<dim3(384, 4, 1), 256, 0, stream>>>(Part, T1, R1);

    // step2: P = Adj @ T1^T  M=3072 N=256 K=3072, S=4
    GArgs g2 = { Adj, SQ_STRIDE, 3, T1, R1, 3,
                 Part, R1, PAD, 256, PAD, PAD, PAD, 256, BIG, BIG };
    gemm_bt<0, 3, 4><<<dim3(24, 2, 16), 256, 0, stream>>>(g2);
    reduce_k<0, 4><<<dim3(384, 4, 1), 256, 0, stream>>>(Part, Z1, R1);

    // step3: T2 = tanh(W2t @ Z1^T)  M=128 N=3072 K=256, direct
    GArgs g3 = { W2t, (size_t)128 * 256, 3, Z1, R1, 3,
                 T2, R2, 128, PAD, 256, 256, 256, PAD, BIG, BIG };
    gemm_bt<1, 0, 1><<<dim3(1, 24, 4), 256, 0, stream>>>(g3);

    // step4: P = Adj @ T2^T  M=3072 N=128 K=3072, S=8
    GArgs g4 = { Adj, SQ_STRIDE, 3, T2, R2, 3,
                 Part, R2, PAD, 128, PAD, PAD, PAD, 128, BIG, BIG };
    gemm_bt<0, 3, 8><<<dim3(24, 1, 32), 256, 0, stream>>>(g4);
    reduce_k<0, 8><<<dim3(192, 4, 1), 256, 0, stream>>>(Part, Z2, R2);

    // step5: T3 = W3t @ Z2^T  M=128 N=3072 K=128, direct
    GArgs g5 = { W3t, (size_t)128 * 128, 3, Z2, R2, 3,
                 T3, R2, 128, PAD, 128, 128, 128, PAD, BIG, BIG };
    gemm_bt<0, 0, 1><<<dim3(1, 24, 4), 256, 0, stream>>>(g5);

    // step6: P = Adj @ T3^T  M=3072 N=128 K=3072, S=8
    GArgs g6 = { Adj, SQ_STRIDE, 3, T3, R2, 3,
                 Part, R2, PAD, 128, PAD, PAD, PAD, 128, BIG, BIG };
    gemm_bt<0, 3, 8><<<dim3(24, 1, 32), 256, 0, stream>>>(g6);
    reduce_k<0, 8><<<dim3(192, 4, 1), 256, 0, stream>>>(Part, Z3, R2);

    // step7: OUT = sigmoid(Z3 @ Z3^T)  M=N=3000 K=64 (cols 64..127 of Z3 zero)
    GArgs g7 = { Z3, R2, 3, Z3, R2, 3,
                 d_out, (size_t)MR * MR, MR, MR, 64, 128, 128, MR, MR, MR };
    gemm_bt<0, 2, 1><<<dim3(24, 24, 4), 256, 0, stream>>>(g7);
}

// Round 7
// 261.632 us; speedup vs baseline: 1.1220x; 1.0512x over previous
//
#include <hip/hip_runtime.h>
#include <stdint.h>
#include <stddef.h>

// ---------------------------------------------------------------------------
// 4 GAE encoders, fp16 MFMA. All GEMMs: C = A @ B^T (A:[M][lda], B:[N][ldb]),
// both operands fp16 staged via global_load_lds, BK=32 DOUBLE-BUFFERED
// (stage half-tile h+1 while computing h; one barrier per half-tile).
//   prep2 : grid-stride (1920 blk) X1,X2 + 4 adj -> fp16 padded [3072][3072];
//           128 blk: 12 weights -> fp16 transposed (LDS 64x64 tiles)
//   step1 : P16 = W1t @ Xh^T  (S=4);  T1 = tanh(reduce P16)
//   step2 : P16 = Adj @ T1^T  (S=4);  Z1 = reduce P16
//   step3 : T2 = tanh(W2t @ Z1^T)     (direct)
//   step4 : P16 = Adj @ T2^T  (S=8);  Z2 = reduce P16
//   step5 : T3 = W3t @ Z2^T           (direct)
//   step6 : P16 = Adj @ T3^T  (S=8);  Z3 = reduce P16
//   step7 : OUT = sigmoid(Z3 @ Z3^T), K=64  (fp32 NT stores)
// d_out layout: [4 x fp16 Adj 75.5 MB][fp16 split-K partials <=25.2 MB]
// (both dead before step7 overwrites d_out).
// ---------------------------------------------------------------------------

typedef __attribute__((ext_vector_type(8))) _Float16 half8;
typedef __attribute__((ext_vector_type(4))) float f32x4;

#define PAD 3072
#define MR  3000
#define SQ_STRIDE ((size_t)PAD * PAD)
#define CAST_BLK 1920
#define WT_BLK   128

static __device__ __forceinline__ void async_cp16(const _Float16* g, _Float16* l) {
    __builtin_amdgcn_global_load_lds((const __attribute__((address_space(1))) void*)g,
                                     (__attribute__((address_space(3))) void*)l, 16, 0, 0);
}

// ---------------- prep2: grid-stride casts + weight transposes ----------
struct PrepArgs {
    const float* csrc[6];  _Float16* cdst[6];   // X1,X2,adj0..3
    const float* Wsrc[12]; _Float16* Wdst[3];   // W1t, W2t, W3t bases
};

__global__ __launch_bounds__(256) void prep2(PrepArgs p) {
    __shared__ _Float16 lt[64 * 64];
    const int b = blockIdx.x;
    const int t = threadIdx.x;
    if (b < CAST_BLK) {
        // fp32 [3000][3000] -> fp16 [3072][3072] zero-padded; 8 floats/lane/iter
        const int UPA = PAD * PAD / 8;          // 1,179,648 units per array
        const int TOT = 6 * UPA;
        for (int u = b * 256 + t; u < TOT; u += CAST_BLK * 256) {
            const int arr = u / UPA;
            const int rem = u - arr * UPA;
            const int row = rem / 384;
            const int c0  = (rem - row * 384) * 8;   // 8 | 3000 -> clean boundary
            half8 h;
            if (row < MR && c0 < MR) {
                const float* sp = p.csrc[arr] + (size_t)row * MR + c0;
                f32x4 v0 = *(const f32x4*)sp;
                f32x4 v1 = *(const f32x4*)(sp + 4);
                #pragma unroll
                for (int j = 0; j < 4; ++j) { h[j] = (_Float16)v0[j]; h[4 + j] = (_Float16)v1[j]; }
            } else {
                #pragma unroll
                for (int j = 0; j < 8; ++j) h[j] = (_Float16)0.f;
            }
            *(half8*)(p.cdst[arr] + (size_t)row * PAD + c0) = h;
        }
    } else {
        // weight transpose-cast: src [fi][fo] fp32 -> dst [fo_pad][ldk] fp16
        // per-enc tiles: W1 48x4=192, W2 4x2=8, W3 2x2=4  (204/enc, 816 total)
        for (int tile = b - CAST_BLK; tile < 816; tile += WT_BLK) {
            const int enc = tile / 204;
            int rem = tile - enc * 204;
            const float* src; _Float16* dst; int fi, fo, ldk, kt, rt;
            if (rem < 192) {
                src = p.Wsrc[enc * 3 + 0]; dst = p.Wdst[0] + (size_t)enc * 256 * PAD;
                fi = MR; fo = 256; ldk = PAD; kt = rem >> 2; rt = rem & 3;
            } else if (rem < 200) {
                rem -= 192;
                src = p.Wsrc[enc * 3 + 1]; dst = p.Wdst[1] + (size_t)enc * 128 * 256;
                fi = 256; fo = 128; ldk = 256; kt = rem >> 1; rt = rem & 1;
            } else {
                rem -= 200;
                src = p.Wsrc[enc * 3 + 2]; dst = p.Wdst[2] + (size_t)enc * 128 * 128;
                fi = 128; fo = 64; ldk = 128; kt = rem >> 1; rt = rem & 1;
            }
            const int k0 = kt * 64, r0 = rt * 64;
            __syncthreads();   // protect lt from previous iteration's readers
            {
                const int kr = t >> 2, cc = (t & 3) << 4;
                const int gk = k0 + kr;
                const bool kok = gk < fi;
                #pragma unroll
                for (int j = 0; j < 16; ++j) {
                    const int gr = r0 + cc + j;
                    const float v = (kok && gr < fo) ? src[(size_t)gk * fo + gr] : 0.f;
                    lt[(cc + j) * 64 + kr] = (_Float16)v;
                }
            }
            __syncthreads();
            {
                const int rr = t >> 2, kk = (t & 3) << 4;
                half8 a  = *(half8*)&lt[rr * 64 + kk];
                half8 bb = *(half8*)&lt[rr * 64 + kk + 8];
                _Float16* dp = dst + (size_t)(r0 + rr) * ldk + k0 + kk;
                *(half8*)dp = a;
                *(half8*)(dp + 8) = bb;
            }
        }
    }
}

// ---------------- GEMM: C = A @ B^T, BK=32 double-buffered ----------------
struct GArgs {
    const _Float16* Aall; size_t aStride; int aMask;
    const _Float16* Ball; size_t bStride; int bMask;
    void* Call; size_t cStride;
    int M, Ncols, Kp, lda, ldb, ldc, mBound, nBound;
};

// OMODE: 0 = direct fp16 (opt tanh via ACT), 1 = fp16 partial z-indexed
//        (LDS repack, half8 stores), 2 = fp32 sigmoid (LDS repack, NT stores).
// S = split-K factor.
template<int ACT, int OMODE, int S>
__global__ __launch_bounds__(256, 3)
void gemm_bt(GArgs ga)
{
    // smem: [2 bufs][ As:128x32 | Bs:128x32 ] fp16 = 32 KB total
    __shared__ _Float16 smem[16384];

    const int z   = blockIdx.z;
    const int e   = z / S;
    const int ksl = z - e * S;
    const int Kslice = ga.Kp / S;
    const int kbase  = ksl * Kslice;

    const _Float16* A = ga.Aall + (size_t)(e & ga.aMask) * ga.aStride;
    const _Float16* B = ga.Ball + (size_t)(e & ga.bMask) * ga.bStride;

    const int tm = blockIdx.x * 128;
    const int tn = blockIdx.y * 128;
    const int t    = threadIdx.x;
    const int lane = t & 63;
    const int w    = t >> 6;
    const int wm   = (w >> 1) * 64;
    const int wn   = (w & 1) * 64;
    const int lr   = lane & 15;
    const int lg   = lane >> 4;

    // staging coords: 512 chunk-slots of 16 B per operand per half-tile
    const int sr  = t >> 2;    // row (first 64), +64 on second iter
    const int sch = t & 3;     // 16B chunk within 32-half row

    f32x4 acc[4][4];
    const f32x4 zero = {0.f, 0.f, 0.f, 0.f};
    #pragma unroll
    for (int i = 0; i < 4; ++i)
        #pragma unroll
        for (int j = 0; j < 4; ++j) acc[i][j] = zero;

    const int nht = Kslice >> 5;   // half-tiles of K=32

    auto STAGE = [&](int ht, int buf) {
        const int k0 = kbase + (ht << 5);
        _Float16* As = smem + buf * 8192;
        _Float16* Bs = As + 4096;
        #pragma unroll
        for (int i = 0; i < 2; ++i) {
            const int row = sr + i * 64;
            const int sc  = sch ^ (row & 3);   // pre-swizzled source chunk
            async_cp16(A + (size_t)(tm + row) * ga.lda + k0 + sc * 8,
                       As + (row * 4 + sch) * 8);
        }
        #pragma unroll
        for (int i = 0; i < 2; ++i) {
            const int row = sr + i * 64;
            const int sc  = sch ^ (row & 3);
            async_cp16(B + (size_t)(tn + row) * ga.ldb + k0 + sc * 8,
                       Bs + (row * 4 + sch) * 8);
        }
    };

    STAGE(0, 0);
    __syncthreads();
    for (int h = 0; h < nht; ++h) {
        const int cur = h & 1;
        if (h + 1 < nht) STAGE(h + 1, cur ^ 1);   // overlap with compute below
        const _Float16* As = smem + cur * 8192;
        const _Float16* Bs = As + 4096;
        half8 af[4], bf[4];
        #pragma unroll
        for (int mi = 0; mi < 4; ++mi) {
            const int ra = wm + mi * 16 + lr;
            const int ch = lg ^ (ra & 3);
            af[mi] = *(const half8*)(As + ra * 32 + ch * 8);
        }
        #pragma unroll
        for (int ni = 0; ni < 4; ++ni) {
            const int rb = wn + ni * 16 + lr;
            const int ch = lg ^ (rb & 3);
            bf[ni] = *(const half8*)(Bs + rb * 32 + ch * 8);
        }
        #pragma unroll
        for (int mi = 0; mi < 4; ++mi)
            #pragma unroll
            for (int ni = 0; ni < 4; ++ni)
                acc[mi][ni] = __builtin_amdgcn_mfma_f32_16x16x32_f16(
                    af[mi], bf[ni], acc[mi][ni], 0, 0, 0);
        __syncthreads();   // drains vmcnt (next buf ready) + reads-done
    }

    // epilogue. D layout: col = lane&15, row = 4*(lane>>4)+reg (m89-verified).
    if (OMODE == 0) {
        _Float16* C = (_Float16*)ga.Call + (size_t)e * ga.cStride;
        #pragma unroll
        for (int mi = 0; mi < 4; ++mi)
            #pragma unroll
            for (int rr = 0; rr < 4; ++rr) {
                const int m = tm + wm + mi * 16 + lg * 4 + rr;
                #pragma unroll
                for (int ni = 0; ni < 4; ++ni) {
                    const int n = tn + wn + ni * 16 + lr;
                    float x = acc[mi][ni][rr];
                    if (ACT) x = tanhf(x);
                    const bool ok = (m < ga.M) && (n < ga.Ncols);
                    C[(size_t)m * ga.ldc + n] = ok ? (_Float16)x : (_Float16)0.f;
                }
            }
    } else if (OMODE == 1) {
        // fp16 partial, z-indexed: per-wave 32x64 fp16 LDS repack, half8 stores
        _Float16* Cp = (_Float16*)ga.Call + (size_t)z * ga.cStride;
        _Float16* ep = smem + w * 2048;
        #pragma unroll
        for (int hs = 0; hs < 2; ++hs) {
            __syncthreads();
            #pragma unroll
            for (int mi2 = 0; mi2 < 2; ++mi2)
                #pragma unroll
                for (int ni = 0; ni < 4; ++ni)
                    #pragma unroll
                    for (int rr = 0; rr < 4; ++rr) {
                        const int row = mi2 * 16 + lg * 4 + rr;
                        const int col = ni * 16 + lr;
                        const int sw  = (((row ^ (row >> 2)) & 3) << 4);
                        ep[row * 64 + (col ^ sw)] = (_Float16)acc[hs * 2 + mi2][ni][rr];
                    }
            __syncthreads();
            #pragma unroll
            for (int it = 0; it < 4; ++it) {
                const int row = it * 8 + (lane >> 3);
                const int c0  = (lane & 7) * 8;
                const int sw  = (((row ^ (row >> 2)) & 3) << 4);
                half8 v = *(const half8*)&ep[row * 64 + (c0 ^ sw)];
                const int gm = tm + wm + hs * 32 + row;
                const int gn = tn + wn + c0;
                *(half8*)&Cp[(size_t)gm * ga.ldc + gn] = v;
            }
        }
    } else {
        // fp32 sigmoid: per-wave 32x64 fp32 LDS repack, f32x4 NT stores
        float* Cp = (float*)ga.Call + (size_t)e * ga.cStride;
        float* ep = (float*)smem + w * 2048;
        #pragma unroll
        for (int hs = 0; hs < 2; ++hs) {
            __syncthreads();
            #pragma unroll
            for (int mi2 = 0; mi2 < 2; ++mi2)
                #pragma unroll
                for (int ni = 0; ni < 4; ++ni)
                    #pragma unroll
                    for (int rr = 0; rr < 4; ++rr) {
                        const int row = mi2 * 16 + lg * 4 + rr;
                        const int col = ni * 16 + lr;
                        const int sw  = (((row ^ (row >> 2)) & 3) << 4);
                        ep[row * 64 + (col ^ sw)] = acc[hs * 2 + mi2][ni][rr];
                    }
            __syncthreads();
            #pragma unroll
            for (int r2 = 0; r2 < 8; ++r2) {
                const int row = r2 * 4 + (lane >> 4);
                const int c4  = (lane & 15) * 4;
                const int sw  = (((row ^ (row >> 2)) & 3) << 4);
                f32x4 v = *(const f32x4*)&ep[row * 64 + (c4 ^ sw)];
                const int gm = tm + wm + hs * 32 + row;
                const int gn = tn + wn + c4;
                if (gm < ga.mBound && gn < ga.nBound) {
                    #pragma unroll
                    for (int j = 0; j < 4; ++j)
                        v[j] = 1.0f / (1.0f + __expf(-v[j]));
                    __builtin_nontemporal_store(v, (f32x4*)&Cp[(size_t)gm * ga.ldc + gn]);
                }
            }
        }
    }
}

// ---------------- split-K reduce: out = act(sum_s P16[s]) in fp16 ----------
template<int ACT, int S>
__global__ __launch_bounds__(256)
void reduce_k(const _Float16* __restrict__ P, _Float16* __restrict__ out, size_t region)
{
    const size_t e    = blockIdx.y;
    const size_t base = (size_t)(blockIdx.x * 256 + threadIdx.x) * 8;
    const _Float16* p0 = P + e * S * region + base;
    float s[8] = {0.f, 0.f, 0.f, 0.f, 0.f, 0.f, 0.f, 0.f};
    #pragma unroll
    for (int si = 0; si < S; ++si) {
        half8 v = *(const half8*)(p0 + (size_t)si * region);
        #pragma unroll
        for (int j = 0; j < 8; ++j) s[j] += (float)v[j];
    }
    half8 h;
    #pragma unroll
    for (int j = 0; j < 8; ++j) {
        float x = s[j];
        if (ACT) x = tanhf(x);
        h[j] = (_Float16)x;
    }
    *(half8*)(out + e * region + base) = h;
}

// ---------------- launcher ----------------
extern "C" void kernel_launch(void* const* d_in, const int* in_sizes, int n_in,
                              void* d_out, int out_size, void* d_ws, size_t ws_size,
                              hipStream_t stream)
{
    const size_t R1 = 786432;   // 256*3072 and 3072*256
    const size_t R2 = 393216;   // 128*3072 and 3072*128

    // d_out layout: [4 x fp16 Adj (75.5 MB)][fp16 partials (<=25.2 MB)]
    _Float16* Adj    = (_Float16*)d_out;
    _Float16* Part16 = Adj + 4 * SQ_STRIDE;

    _Float16* hb = (_Float16*)d_ws;
    size_t off = 0;
    auto alloc = [&](size_t elems) { _Float16* p = hb + off; off += elems; return p; };
    _Float16* Xh  = alloc(2 * SQ_STRIDE);
    _Float16* T1  = alloc(4 * R1);
    _Float16* Z1  = alloc(4 * R1);
    _Float16* T2  = alloc(4 * R2);
    _Float16* Z2  = alloc(4 * R2);
    _Float16* T3  = alloc(4 * R2);
    _Float16* Z3  = alloc(4 * R2);
    _Float16* W1t = alloc(4ull * 256 * PAD);
    _Float16* W2t = alloc(4ull * 128 * 256);
    _Float16* W3t = alloc(4ull * 128 * 128);

    // prep: grid-stride casts + weight transposes
    PrepArgs pa;
    pa.csrc[0] = (const float*)d_in[0]; pa.cdst[0] = Xh;
    pa.csrc[1] = (const float*)d_in[1]; pa.cdst[1] = Xh + SQ_STRIDE;
    for (int i = 0; i < 4; ++i) {
        pa.csrc[2 + i] = (const float*)d_in[2 + i];
        pa.cdst[2 + i] = Adj + (size_t)i * SQ_STRIDE;
    }
    for (int enc = 0; enc < 4; ++enc)
        for (int li = 0; li < 3; ++li)
            pa.Wsrc[enc * 3 + li] = (const float*)d_in[6 + enc * 3 + li];
    pa.Wdst[0] = W1t; pa.Wdst[1] = W2t; pa.Wdst[2] = W3t;
    prep2<<<dim3(CAST_BLK + WT_BLK, 1, 1), 256, 0, stream>>>(pa);

    const int BIG = 1 << 30;

    // step1: P16 = W1t @ Xh^T  M=256 N=3072 K=3072, S=4
    GArgs g1 = { W1t, (size_t)256 * PAD, 3, Xh, SQ_STRIDE, 1,
                 Part16, R1, 256, PAD, PAD, PAD, PAD, PAD, BIG, BIG };
    gemm_bt<0, 1, 4><<<dim3(2, 24, 16), 256, 0, stream>>>(g1);
    reduce_k<1, 4><<<dim3(384, 4, 1), 256, 0, stream>>>(Part16, T1, R1);

    // step2: P16 = Adj @ T1^T  M=3072 N=256 K=3072, S=4
    GArgs g2 = { Adj, SQ_STRIDE, 3, T1, R1, 3,
                 Part16, R1, PAD, 256, PAD, PAD, PAD, 256, BIG, BIG };
    gemm_bt<0, 1, 4><<<dim3(24, 2, 16), 256, 0, stream>>>(g2);
    reduce_k<0, 4><<<dim3(384, 4, 1), 256, 0, stream>>>(Part16, Z1, R1);

    // step3: T2 = tanh(W2t @ Z1^T)  M=128 N=3072 K=256, direct
    GArgs g3 = { W2t, (size_t)128 * 256, 3, Z1, R1, 3,
                 T2, R2, 128, PAD, 256, 256, 256, PAD, BIG, BIG };
    gemm_bt<1, 0, 1><<<dim3(1, 24, 4), 256, 0, stream>>>(g3);

    // step4: P16 = Adj @ T2^T  M=3072 N=128 K=3072, S=8
    GArgs g4 = { Adj, SQ_STRIDE, 3, T2, R2, 3,
                 Part16, R2, PAD, 128, PAD, PAD, PAD, 128, BIG, BIG };
    gemm_bt<0, 1, 8><<<dim3(24, 1, 32), 256, 0, stream>>>(g4);
    reduce_k<0, 8><<<dim3(192, 4, 1), 256, 0, stream>>>(Part16, Z2, R2);

    // step5: T3 = W3t @ Z2^T  M=128 N=3072 K=128, direct
    GArgs g5 = { W3t, (size_t)128 * 128, 3, Z2, R2, 3,
                 T3, R2, 128, PAD, 128, 128, 128, PAD, BIG, BIG };
    gemm_bt<0, 0, 1><<<dim3(1, 24, 4), 256, 0, stream>>>(g5);

    // step6: P16 = Adj @ T3^T  M=3072 N=128 K=3072, S=8
    GArgs g6 = { Adj, SQ_STRIDE, 3, T3, R2, 3,
                 Part16, R2, PAD, 128, PAD, PAD, PAD, 128, BIG, BIG };
    gemm_bt<0, 1, 8><<<dim3(24, 1, 32), 256, 0, stream>>>(g6);
    reduce_k<0, 8><<<dim3(192, 4, 1), 256, 0, stream>>>(Part16, Z3, R2);

    // step7: OUT = sigmoid(Z3 @ Z3^T)  M=N=3000 K=64 (cols 64..127 of Z3 zero)
    GArgs g7 = { Z3, R2, 3, Z3, R2, 3,
                 d_out, (size_t)MR * MR, MR, MR, 64, 128, 128, MR, MR, MR };
    gemm_bt<0, 2, 1><<<dim3(24, 24, 4), 256, 0, stream>>>(g7);
}